// Round 17
// baseline (90.956 us; speedup 1.0000x reference)
//
#include <hip/hip_runtime.h>

#define B_ 2
#define T_ 8
#define Z_ 20
#define Y_ 64
#define X_ 64
#define C_ 2
#define F1_ 32
#define F_ 32

constexpr int NPTS = B_*T_*Z_*Y_*X_;   // 1,310,720
constexpr int ZYX  = Z_*Y_*X_;         // 81,920

constexpr int RING_STRIDE = 36;            // dwords/row (16B-aligned rows)
constexpr int SLOT_DW     = 16*RING_STRIDE;// 576 dwords per ring slot
constexpr int HALO2       = 3*3*34;        // 306 uint2 per wave per t (32x span)
constexpr int REPACK_BLKS = NPTS/256;      // 5120

using bf8   = __attribute__((ext_vector_type(8))) short;
using f32x4 = __attribute__((ext_vector_type(4))) float;

__device__ inline unsigned short f2bf(float x) {   // RNE float->bf16
    unsigned u = __builtin_bit_cast(unsigned, x);
    return (unsigned short)((u + 0x7fff + ((u >> 16) & 1)) >> 16);
}
__device__ inline unsigned pk(float a, float b) {  // pack 2 bf16 into dword
    return (unsigned)f2bf(a) | ((unsigned)f2bf(b) << 16);
}

// ---------------------------------------------------------------------------
// prep_kernel: 5160 INDEPENDENT blocks (verified round-16 version, unchanged).
// ---------------------------------------------------------------------------
__global__ __launch_bounds__(256) void prep_kernel(
    const float* __restrict__ wxr, const float* __restrict__ wxi,
    const float* __restrict__ wtr, const float* __restrict__ wti,
    const float* __restrict__ xr,  const float* __restrict__ xi,
    unsigned short* __restrict__ wsp, unsigned short* __restrict__ wp,
    uint2* __restrict__ xb)
{
    const int tid = threadIdx.x;

    if (blockIdx.x < REPACK_BLKS) {
        const int p = blockIdx.x*256 + tid;
        const float2 vr = *reinterpret_cast<const float2*>(xr + (size_t)p*2);
        const float2 vi = *reinterpret_cast<const float2*>(xi + (size_t)p*2);
        xb[p] = make_uint2(pk(vr.x, vr.y), pk(vi.x, vi.y));
        return;
    }

    __shared__ float s_a[96*F_], s_b[96*F_];
    const int lane = tid & 63;
    const int w    = tid >> 6;
    const int g2   = blockIdx.x - REPACK_BLKS;   // 0..39

    if (g2 < 16) {
        for (int i = 0; i < 8; ++i) {
            const int f = w*8 + i;
            float er = 0.f, ei = 0.f;
            if (lane < 54) { er = wxr[lane*F1_ + f]; ei = wxi[lane*F1_ + f]; }
            float sr = er, si = ei;
            #pragma unroll
            for (int o = 32; o >= 1; o >>= 1) { sr += __shfl_xor(sr, o); si += __shfl_xor(si, o); }
            const float mr = sr * (1.f/54.f), mi = si * (1.f/54.f);
            const float dr = er - mr, di = ei - mi;
            float sq = (lane < 54) ? (dr*dr + di*di) : 0.f;
            #pragma unroll
            for (int o = 32; o >= 1; o >>= 1) sq += __shfl_xor(sq, o);
            const float s = 1.f / fmaxf(sqrtf(sq), 1.f);
            if (lane < 54) { s_a[lane*F1_ + f] = dr*s; s_b[lane*F1_ + f] = di*s; }
        }
        __syncthreads();
        for (int o = g2*512 + tid; o < g2*512 + 512; o += 256) {
            const int j  = o & 7;
            const int l  = (o >> 3) & 63;
            const int gg = o >> 9;
            const int kb = gg & 3, ct = gg >> 2;
            const int k  = kb*32 + (l >> 4)*8 + j;
            const int n  = ct*16 + (l & 15);
            float v = 0.f;
            if (k < 108) {
                const int tap = k >> 2, q = k & 3, cin = q & 1, cp = q >> 1;
                const int f  = n & 31;
                const float wr_ = s_a[(tap*2 + cin)*F1_ + f];
                const float wi_ = s_b[(tap*2 + cin)*F1_ + f];
                v = (n < 32) ? (cp ? -wi_ : wr_) : (cp ? wr_ : wi_);
            }
            wsp[o] = f2bf(v);
        }
    } else {
        for (int i = 0; i < 8; ++i) {
            const int f = w*8 + i;
            float er[2], ei[2];
            float sq = 0.f;
            #pragma unroll
            for (int k = 0; k < 2; ++k) {
                const int e = lane + k*64;
                if (e < 96) { er[k] = wtr[e*F_ + f]; ei[k] = wti[e*F_ + f]; sq += er[k]*er[k] + ei[k]*ei[k]; }
                else        { er[k] = 0.f;  ei[k] = 0.f; }
            }
            #pragma unroll
            for (int o = 32; o >= 1; o >>= 1) sq += __shfl_xor(sq, o);
            const float s = 1.f / fmaxf(sqrtf(sq), 1.f);
            #pragma unroll
            for (int k = 0; k < 2; ++k) {
                const int e = lane + k*64;
                if (e < 96) { s_a[e*F_ + f] = er[k]*s; s_b[e*F_ + f] = ei[k]*s; }
            }
        }
        __syncthreads();
        const int gt = g2 - 16;
        for (int o = gt*512 + tid; o < gt*512 + 512; o += 256) {
            const int j  = o & 7;
            const int l  = (o >> 3) & 63;
            const int gg = o >> 9;          // ct*6 + kb
            const int kb = gg % 6, ct = gg / 6;
            const int k  = kb*32 + (l >> 4)*8 + j;
            const int n  = ct*16 + (l & 15);
            const int kt = k >> 6, f1 = (k >> 1) & 31, c = k & 1;
            const int f  = n & 31;
            const float wr_ = s_a[(kt*F1_ + f1)*F_ + f];
            const float wi_ = s_b[(kt*F1_ + f1)*F_ + f];
            const float v   = (n < 32) ? (c ? -wi_ : wr_) : (c ? wr_ : wi_);
            wp[o] = f2bf(v);
        }
    }
}

// ---------------------------------------------------------------------------
// Fused kernel, DUAL X-TILE — round-16 structure; SINGLE change: t-loop
// unrolled 2x so the scheduler can hoist iteration t+1's independent loads
// and ring reads into iteration t's waitcnt stall windows.
// ---------------------------------------------------------------------------
__global__ __launch_bounds__(256, 2) void fused_kernel(
    const uint2* __restrict__ xb,
    const unsigned short* __restrict__ wsp,
    const unsigned short* __restrict__ wp,
    float* __restrict__ yr, float* __restrict__ yi)
{
    __shared__ uint4 ring4[4*2*3*SLOT_DW/4];   // 55.3 KB (4 waves x 2 tiles)
    __shared__ uint2 slab[4][2][HALO2];        // 19.6 KB
    unsigned* ring = reinterpret_cast<unsigned*>(ring4);

    const int tid  = threadIdx.x;
    const int lane = tid & 63;
    const int wid  = tid >> 6;
    const int lx   = lane & 15;
    const int lg   = lane >> 4;

    const int bq    = blockIdx.x;        // b*Z*32 + z*32 + ypair
    const int ypair = bq & 31;           // Y/2 = 32
    const int z     = (bq >> 5) % Z_;
    const int b     = bq / (32*Z_);
    const int y     = ypair*2 + (wid >> 1);
    const int x0    = (wid & 1) * 32;

    // ---- weight fragments (A-operands; verified bytes) ----
    bf8 wsf[4][4];
    const bf8* w8 = reinterpret_cast<const bf8*>(wsp);
    #pragma unroll
    for (int ct = 0; ct < 4; ++ct)
        #pragma unroll
        for (int kb = 0; kb < 4; ++kb)
            wsf[ct][kb] = w8[(ct*4 + kb)*64 + lane];

    bf8 wtf[4][6];
    const bf8* wp8 = reinterpret_cast<const bf8*>(wp);
    #pragma unroll
    for (int ct = 0; ct < 4; ++ct)
        #pragma unroll
        for (int kb = 0; kb < 6; ++kb)
            wtf[ct][kb] = wp8[(ct*6 + kb)*64 + lane];

    // ---- staging offsets: 5 slots covering 306 halo points ----
    int xoff[5];
    #pragma unroll
    for (int i = 0; i < 5; ++i) {
        int it = lane + i*64; if (it >= HALO2) it = HALO2-1;  // dup, write-guarded
        const int iz = it / 102;         // 102 = 3y*34x
        const int iy = (it / 34) % 3;
        const int ix = it % 34;
        int zz = z + iz - 1;  zz = zz < 0 ? 0 : (zz >= Z_ ? Z_-1 : zz);
        int yy = y + iy - 1;  yy = yy < 0 ? 0 : (yy >= Y_ ? Y_-1 : yy);
        int xx = x0 + ix - 1; xx = xx < 0 ? 0 : (xx >= X_ ? X_-1 : xx);
        xoff[i] = (zz*Y_ + yy)*X_ + xx;
    }

    // ---- per-lane slab read offsets for the A-gather (tile A; +16 for B) ----
    int o8[4][2];
    #pragma unroll
    for (int kb = 0; kb < 4; ++kb)
        #pragma unroll
        for (int s = 0; s < 2; ++s) {
            int ta = kb*8 + lg*2 + s; if (ta > 26) ta = 26;   // k>=108: B is 0
            const int dz = ta/9, dyx = ta - dz*9, dy = dyx/3, dx = dyx - dy*3;
            o8[kb][s] = (dz*3 + dy)*34 + dx + lx;
        }

    unsigned* myring  = ring + wid*(2*3*SLOT_DW);
    const int  rbase  = lx*RING_STRIDE + lg*4;   // dword offset within a slot
    const size_t orow = (((size_t)b*T_)*Z_ + z)*(size_t)(Y_*X_) + (size_t)y*X_ + x0 + lx;

    uint4 caLo, caHi, cbLo, cbHi;                // current slices, tiles A/B
    uint2 stmp[5];                               // in-flight halo loads

    auto STAGE_ISSUE = [&](int t) {              // coalesced, issued early
        const uint2* xt = xb + (size_t)(b*T_ + t)*ZYX;
        #pragma unroll
        for (int i = 0; i < 4; ++i) stmp[i] = xt[xoff[i]];
        if (lane < HALO2 - 256) stmp[4] = xt[xoff[4]];
    };
    auto STAGE_WRITE = [&](int bufsel) {
        uint2* s = slab[wid][bufsel];
        #pragma unroll
        for (int i = 0; i < 4; ++i) s[lane + i*64] = stmp[i];
        if (lane < HALO2 - 256) s[lane + 256] = stmp[4];
    };

    // spatial MFMA for one tile: slab -> (lo,hi) in temporal-B-fragment layout
    auto SPATIAL = [&](int bufsel, int xadd, uint4& lo, uint4& hi) {
        const uint2* s = slab[wid][bufsel];
        bf8 af[4];
        #pragma unroll
        for (int kb = 0; kb < 4; ++kb) {
            const uint2 l2 = s[o8[kb][0] + xadd];
            const uint2 h2 = s[o8[kb][1] + xadd];
            af[kb] = __builtin_bit_cast(bf8, make_uint4(l2.x, l2.y, h2.x, h2.y));
        }
        f32x4 acc[4];
        #pragma unroll
        for (int ct = 0; ct < 4; ++ct) acc[ct] = (f32x4){0.f,0.f,0.f,0.f};
        __builtin_amdgcn_s_setprio(1);
        #pragma unroll
        for (int ct = 0; ct < 4; ++ct)
            #pragma unroll
            for (int kb = 0; kb < 4; ++kb)
                acc[ct] = __builtin_amdgcn_mfma_f32_16x16x32_bf16(
                              wsf[ct][kb], af[kb], acc[ct], 0, 0, 0);
        __builtin_amdgcn_s_setprio(0);
        lo = make_uint4(pk(acc[0][0],acc[2][0]), pk(acc[0][1],acc[2][1]),
                        pk(acc[0][2],acc[2][2]), pk(acc[0][3],acc[2][3]));
        hi = make_uint4(pk(acc[1][0],acc[3][0]), pk(acc[1][1],acc[3][1]),
                        pk(acc[1][2],acc[3][2]), pk(acc[1][3],acc[3][3]));
    };

    auto WRITE = [&](int tsel, int t, const uint4& lo, const uint4& hi) {
        unsigned* s = myring + tsel*(3*SLOT_DW) + (t % 3)*SLOT_DW + rbase;
        *reinterpret_cast<uint4*>(s)      = lo;
        *reinterpret_cast<uint4*>(s + 16) = hi;
    };

    // y(tout) for one tile: kt0/kt1 from ring, kt2 = cur regs
    auto EMIT = [&](int tsel, const uint4& clo, const uint4& chi,
                    int sa, int sb, int tout) {
        const unsigned* tb = myring + tsel*(3*SLOT_DW);
        const unsigned* pa = tb + (sa % 3)*SLOT_DW + rbase;
        const unsigned* pb = tb + (sb % 3)*SLOT_DW + rbase;
        bf8 fr[6];
        fr[0] = __builtin_bit_cast(bf8, *reinterpret_cast<const uint4*>(pa));
        fr[1] = __builtin_bit_cast(bf8, *reinterpret_cast<const uint4*>(pa + 16));
        fr[2] = __builtin_bit_cast(bf8, *reinterpret_cast<const uint4*>(pb));
        fr[3] = __builtin_bit_cast(bf8, *reinterpret_cast<const uint4*>(pb + 16));
        fr[4] = __builtin_bit_cast(bf8, clo);
        fr[5] = __builtin_bit_cast(bf8, chi);
        f32x4 acc[4];
        #pragma unroll
        for (int ct = 0; ct < 4; ++ct) acc[ct] = (f32x4){0.f,0.f,0.f,0.f};
        __builtin_amdgcn_s_setprio(1);
        #pragma unroll
        for (int ct = 0; ct < 4; ++ct)
            #pragma unroll
            for (int kb = 0; kb < 6; ++kb)
                acc[ct] = __builtin_amdgcn_mfma_f32_16x16x32_bf16(
                              wtf[ct][kb], fr[kb], acc[ct], 0, 0, 0);
        __builtin_amdgcn_s_setprio(0);
        const size_t p = orow + tsel*16 + (size_t)tout * ZYX;
        #pragma unroll
        for (int ct = 0; ct < 4; ++ct) {
            float* outp = (ct < 2) ? yr : yi;
            *reinterpret_cast<f32x4*>(outp + p*F_ + (ct & 1)*16 + lg*4) = acc[ct];
        }
    };

    // prologue: slab0 = t=0; t=1 loads in flight
    STAGE_ISSUE(0);
    STAGE_WRITE(0);
    STAGE_ISSUE(1);
    SPATIAL(0, 0,  caLo, caHi);
    SPATIAL(0, 16, cbLo, cbHi);
    WRITE(0, 0, caLo, caHi);
    WRITE(1, 0, cbLo, cbHi);

    #pragma unroll 2
    for (int t = 1; t < T_; ++t) {
        STAGE_WRITE(t & 1);                 // complete slab(t)
        if (t < T_-1) STAGE_ISSUE(t+1);     // issue next halo immediately
        const int sa = t-2 < 0 ? 0 : t-2;
        SPATIAL(t & 1, 0,  caLo, caHi);     // two independent MFMA chains
        SPATIAL(t & 1, 16, cbLo, cbHi);
        EMIT(0, caLo, caHi, sa, t-1, t-1);
        EMIT(1, cbLo, cbHi, sa, t-1, t-1);
        WRITE(0, t, caLo, caHi);
        WRITE(1, t, cbLo, cbHi);
    }
    EMIT(0, caLo, caHi, T_-2, T_-1, T_-1);  // y(7) = (s6, s7, s7)
    EMIT(1, cbLo, cbHi, T_-2, T_-1, T_-1);
}

extern "C" void kernel_launch(void* const* d_in, const int* in_sizes, int n_in,
                              void* d_out, int out_size, void* d_ws, size_t ws_size,
                              hipStream_t stream)
{
    const float* xr  = (const float*)d_in[0];
    const float* xi  = (const float*)d_in[1];
    const float* wxr = (const float*)d_in[2];
    const float* wxi = (const float*)d_in[3];
    const float* wtr = (const float*)d_in[4];
    const float* wti = (const float*)d_in[5];

    float* ws   = (float*)d_ws;
    unsigned short* wsp = (unsigned short*)(ws + 12288); // 8192 ushorts (16KB)
    unsigned short* wp  = (unsigned short*)(ws + 16384); // 12288 ushorts (24KB)
    uint2* xb           = (uint2*)(ws + 32768);          // NPTS uint2 (10.5MB)

    float* yr = (float*)d_out;
    float* yi = yr + (size_t)NPTS * F_;

    hipLaunchKernelGGL(prep_kernel, dim3(REPACK_BLKS + 40), dim3(256), 0, stream,
                       wxr, wxi, wtr, wti, xr, xi, wsp, wp, xb);
    hipLaunchKernelGGL(fused_kernel, dim3(B_*Z_*(Y_/2)), dim3(256), 0, stream,
                       xb, wsp, wp, yr, yi);
}

// Round 18
// 89.517 us; speedup vs baseline: 1.0161x; 1.0161x over previous
//
#include <hip/hip_runtime.h>

#define B_ 2
#define T_ 8
#define Z_ 20
#define Y_ 64
#define X_ 64
#define C_ 2
#define F1_ 32
#define F_ 32

constexpr int NPTS = B_*T_*Z_*Y_*X_;   // 1,310,720
constexpr int ZYX  = Z_*Y_*X_;         // 81,920

constexpr int RING_STRIDE = 36;            // dwords/row (16B-aligned rows)
constexpr int SLOT_DW     = 16*RING_STRIDE;// 576 dwords per ring slot
constexpr int HALO2       = 3*3*34;        // 306 uint2 per wave per t (32x span)
constexpr int REPACK_BLKS = NPTS/256;      // 5120

using bf8   = __attribute__((ext_vector_type(8))) short;
using f32x4 = __attribute__((ext_vector_type(4))) float;

__device__ inline unsigned short f2bf(float x) {   // RNE float->bf16
    unsigned u = __builtin_bit_cast(unsigned, x);
    return (unsigned short)((u + 0x7fff + ((u >> 16) & 1)) >> 16);
}
__device__ inline unsigned pk(float a, float b) {  // pack 2 bf16 into dword
    return (unsigned)f2bf(a) | ((unsigned)f2bf(b) << 16);
}

// ---------------------------------------------------------------------------
// prep_kernel: 5160 INDEPENDENT blocks (verified round-16 version, unchanged).
//  - blocks [0, 5120): bf16 input repack.
//  - blocks [5120, 5136): spatial weight pack (redundant per-block projection).
//  - blocks [5136, 5160): temporal weight pack.
// ---------------------------------------------------------------------------
__global__ __launch_bounds__(256) void prep_kernel(
    const float* __restrict__ wxr, const float* __restrict__ wxi,
    const float* __restrict__ wtr, const float* __restrict__ wti,
    const float* __restrict__ xr,  const float* __restrict__ xi,
    unsigned short* __restrict__ wsp, unsigned short* __restrict__ wp,
    uint2* __restrict__ xb)
{
    const int tid = threadIdx.x;

    if (blockIdx.x < REPACK_BLKS) {
        const int p = blockIdx.x*256 + tid;
        const float2 vr = *reinterpret_cast<const float2*>(xr + (size_t)p*2);
        const float2 vi = *reinterpret_cast<const float2*>(xi + (size_t)p*2);
        xb[p] = make_uint2(pk(vr.x, vr.y), pk(vi.x, vi.y));
        return;
    }

    __shared__ float s_a[96*F_], s_b[96*F_];
    const int lane = tid & 63;
    const int w    = tid >> 6;
    const int g2   = blockIdx.x - REPACK_BLKS;   // 0..39

    if (g2 < 16) {
        for (int i = 0; i < 8; ++i) {
            const int f = w*8 + i;
            float er = 0.f, ei = 0.f;
            if (lane < 54) { er = wxr[lane*F1_ + f]; ei = wxi[lane*F1_ + f]; }
            float sr = er, si = ei;
            #pragma unroll
            for (int o = 32; o >= 1; o >>= 1) { sr += __shfl_xor(sr, o); si += __shfl_xor(si, o); }
            const float mr = sr * (1.f/54.f), mi = si * (1.f/54.f);
            const float dr = er - mr, di = ei - mi;
            float sq = (lane < 54) ? (dr*dr + di*di) : 0.f;
            #pragma unroll
            for (int o = 32; o >= 1; o >>= 1) sq += __shfl_xor(sq, o);
            const float s = 1.f / fmaxf(sqrtf(sq), 1.f);
            if (lane < 54) { s_a[lane*F1_ + f] = dr*s; s_b[lane*F1_ + f] = di*s; }
        }
        __syncthreads();
        for (int o = g2*512 + tid; o < g2*512 + 512; o += 256) {
            const int j  = o & 7;
            const int l  = (o >> 3) & 63;
            const int gg = o >> 9;
            const int kb = gg & 3, ct = gg >> 2;
            const int k  = kb*32 + (l >> 4)*8 + j;
            const int n  = ct*16 + (l & 15);
            float v = 0.f;
            if (k < 108) {
                const int tap = k >> 2, q = k & 3, cin = q & 1, cp = q >> 1;
                const int f  = n & 31;
                const float wr_ = s_a[(tap*2 + cin)*F1_ + f];
                const float wi_ = s_b[(tap*2 + cin)*F1_ + f];
                v = (n < 32) ? (cp ? -wi_ : wr_) : (cp ? wr_ : wi_);
            }
            wsp[o] = f2bf(v);
        }
    } else {
        for (int i = 0; i < 8; ++i) {
            const int f = w*8 + i;
            float er[2], ei[2];
            float sq = 0.f;
            #pragma unroll
            for (int k = 0; k < 2; ++k) {
                const int e = lane + k*64;
                if (e < 96) { er[k] = wtr[e*F_ + f]; ei[k] = wti[e*F_ + f]; sq += er[k]*er[k] + ei[k]*ei[k]; }
                else        { er[k] = 0.f;  ei[k] = 0.f; }
            }
            #pragma unroll
            for (int o = 32; o >= 1; o >>= 1) sq += __shfl_xor(sq, o);
            const float s = 1.f / fmaxf(sqrtf(sq), 1.f);
            #pragma unroll
            for (int k = 0; k < 2; ++k) {
                const int e = lane + k*64;
                if (e < 96) { s_a[e*F_ + f] = er[k]*s; s_b[e*F_ + f] = ei[k]*s; }
            }
        }
        __syncthreads();
        const int gt = g2 - 16;
        for (int o = gt*512 + tid; o < gt*512 + 512; o += 256) {
            const int j  = o & 7;
            const int l  = (o >> 3) & 63;
            const int gg = o >> 9;          // ct*6 + kb
            const int kb = gg % 6, ct = gg / 6;
            const int k  = kb*32 + (l >> 4)*8 + j;
            const int n  = ct*16 + (l & 15);
            const int kt = k >> 6, f1 = (k >> 1) & 31, c = k & 1;
            const int f  = n & 31;
            const float wr_ = s_a[(kt*F1_ + f1)*F_ + f];
            const float wi_ = s_b[(kt*F1_ + f1)*F_ + f];
            const float v   = (n < 32) ? (c ? -wi_ : wr_) : (c ? wr_ : wi_);
            wp[o] = f2bf(v);
        }
    }
}

// ---------------------------------------------------------------------------
// Fused kernel, DUAL X-TILE — byte-exact round-16 version (session best,
// 89.75 us): bf16 xb staging, LDS ring, register halo prefetch, setprio.
// ---------------------------------------------------------------------------
__global__ __launch_bounds__(256, 2) void fused_kernel(
    const uint2* __restrict__ xb,
    const unsigned short* __restrict__ wsp,
    const unsigned short* __restrict__ wp,
    float* __restrict__ yr, float* __restrict__ yi)
{
    __shared__ uint4 ring4[4*2*3*SLOT_DW/4];   // 55.3 KB (4 waves x 2 tiles)
    __shared__ uint2 slab[4][2][HALO2];        // 19.6 KB
    unsigned* ring = reinterpret_cast<unsigned*>(ring4);

    const int tid  = threadIdx.x;
    const int lane = tid & 63;
    const int wid  = tid >> 6;
    const int lx   = lane & 15;
    const int lg   = lane >> 4;

    const int bq    = blockIdx.x;        // b*Z*32 + z*32 + ypair
    const int ypair = bq & 31;           // Y/2 = 32
    const int z     = (bq >> 5) % Z_;
    const int b     = bq / (32*Z_);
    const int y     = ypair*2 + (wid >> 1);
    const int x0    = (wid & 1) * 32;

    // ---- weight fragments (A-operands; verified bytes) ----
    bf8 wsf[4][4];
    const bf8* w8 = reinterpret_cast<const bf8*>(wsp);
    #pragma unroll
    for (int ct = 0; ct < 4; ++ct)
        #pragma unroll
        for (int kb = 0; kb < 4; ++kb)
            wsf[ct][kb] = w8[(ct*4 + kb)*64 + lane];

    bf8 wtf[4][6];
    const bf8* wp8 = reinterpret_cast<const bf8*>(wp);
    #pragma unroll
    for (int ct = 0; ct < 4; ++ct)
        #pragma unroll
        for (int kb = 0; kb < 6; ++kb)
            wtf[ct][kb] = wp8[(ct*6 + kb)*64 + lane];

    // ---- staging offsets: 5 slots covering 306 halo points ----
    int xoff[5];
    #pragma unroll
    for (int i = 0; i < 5; ++i) {
        int it = lane + i*64; if (it >= HALO2) it = HALO2-1;  // dup, write-guarded
        const int iz = it / 102;         // 102 = 3y*34x
        const int iy = (it / 34) % 3;
        const int ix = it % 34;
        int zz = z + iz - 1;  zz = zz < 0 ? 0 : (zz >= Z_ ? Z_-1 : zz);
        int yy = y + iy - 1;  yy = yy < 0 ? 0 : (yy >= Y_ ? Y_-1 : yy);
        int xx = x0 + ix - 1; xx = xx < 0 ? 0 : (xx >= X_ ? X_-1 : xx);
        xoff[i] = (zz*Y_ + yy)*X_ + xx;
    }

    // ---- per-lane slab read offsets for the A-gather (tile A; +16 for B) ----
    int o8[4][2];
    #pragma unroll
    for (int kb = 0; kb < 4; ++kb)
        #pragma unroll
        for (int s = 0; s < 2; ++s) {
            int ta = kb*8 + lg*2 + s; if (ta > 26) ta = 26;   // k>=108: B is 0
            const int dz = ta/9, dyx = ta - dz*9, dy = dyx/3, dx = dyx - dy*3;
            o8[kb][s] = (dz*3 + dy)*34 + dx + lx;
        }

    unsigned* myring  = ring + wid*(2*3*SLOT_DW);
    const int  rbase  = lx*RING_STRIDE + lg*4;   // dword offset within a slot
    const size_t orow = (((size_t)b*T_)*Z_ + z)*(size_t)(Y_*X_) + (size_t)y*X_ + x0 + lx;

    uint4 caLo, caHi, cbLo, cbHi;                // current slices, tiles A/B
    uint2 stmp[5];                               // in-flight halo loads

    auto STAGE_ISSUE = [&](int t) {              // coalesced, issued early
        const uint2* xt = xb + (size_t)(b*T_ + t)*ZYX;
        #pragma unroll
        for (int i = 0; i < 4; ++i) stmp[i] = xt[xoff[i]];
        if (lane < HALO2 - 256) stmp[4] = xt[xoff[4]];
    };
    auto STAGE_WRITE = [&](int bufsel) {
        uint2* s = slab[wid][bufsel];
        #pragma unroll
        for (int i = 0; i < 4; ++i) s[lane + i*64] = stmp[i];
        if (lane < HALO2 - 256) s[lane + 256] = stmp[4];
    };

    // spatial MFMA for one tile: slab -> (lo,hi) in temporal-B-fragment layout
    auto SPATIAL = [&](int bufsel, int xadd, uint4& lo, uint4& hi) {
        const uint2* s = slab[wid][bufsel];
        bf8 af[4];
        #pragma unroll
        for (int kb = 0; kb < 4; ++kb) {
            const uint2 l2 = s[o8[kb][0] + xadd];
            const uint2 h2 = s[o8[kb][1] + xadd];
            af[kb] = __builtin_bit_cast(bf8, make_uint4(l2.x, l2.y, h2.x, h2.y));
        }
        f32x4 acc[4];
        #pragma unroll
        for (int ct = 0; ct < 4; ++ct) acc[ct] = (f32x4){0.f,0.f,0.f,0.f};
        __builtin_amdgcn_s_setprio(1);
        #pragma unroll
        for (int ct = 0; ct < 4; ++ct)
            #pragma unroll
            for (int kb = 0; kb < 4; ++kb)
                acc[ct] = __builtin_amdgcn_mfma_f32_16x16x32_bf16(
                              wsf[ct][kb], af[kb], acc[ct], 0, 0, 0);
        __builtin_amdgcn_s_setprio(0);
        lo = make_uint4(pk(acc[0][0],acc[2][0]), pk(acc[0][1],acc[2][1]),
                        pk(acc[0][2],acc[2][2]), pk(acc[0][3],acc[2][3]));
        hi = make_uint4(pk(acc[1][0],acc[3][0]), pk(acc[1][1],acc[3][1]),
                        pk(acc[1][2],acc[3][2]), pk(acc[1][3],acc[3][3]));
    };

    auto WRITE = [&](int tsel, int t, const uint4& lo, const uint4& hi) {
        unsigned* s = myring + tsel*(3*SLOT_DW) + (t % 3)*SLOT_DW + rbase;
        *reinterpret_cast<uint4*>(s)      = lo;
        *reinterpret_cast<uint4*>(s + 16) = hi;
    };

    // y(tout) for one tile: kt0/kt1 from ring, kt2 = cur regs
    auto EMIT = [&](int tsel, const uint4& clo, const uint4& chi,
                    int sa, int sb, int tout) {
        const unsigned* tb = myring + tsel*(3*SLOT_DW);
        const unsigned* pa = tb + (sa % 3)*SLOT_DW + rbase;
        const unsigned* pb = tb + (sb % 3)*SLOT_DW + rbase;
        bf8 fr[6];
        fr[0] = __builtin_bit_cast(bf8, *reinterpret_cast<const uint4*>(pa));
        fr[1] = __builtin_bit_cast(bf8, *reinterpret_cast<const uint4*>(pa + 16));
        fr[2] = __builtin_bit_cast(bf8, *reinterpret_cast<const uint4*>(pb));
        fr[3] = __builtin_bit_cast(bf8, *reinterpret_cast<const uint4*>(pb + 16));
        fr[4] = __builtin_bit_cast(bf8, clo);
        fr[5] = __builtin_bit_cast(bf8, chi);
        f32x4 acc[4];
        #pragma unroll
        for (int ct = 0; ct < 4; ++ct) acc[ct] = (f32x4){0.f,0.f,0.f,0.f};
        __builtin_amdgcn_s_setprio(1);
        #pragma unroll
        for (int ct = 0; ct < 4; ++ct)
            #pragma unroll
            for (int kb = 0; kb < 6; ++kb)
                acc[ct] = __builtin_amdgcn_mfma_f32_16x16x32_bf16(
                              wtf[ct][kb], fr[kb], acc[ct], 0, 0, 0);
        __builtin_amdgcn_s_setprio(0);
        const size_t p = orow + tsel*16 + (size_t)tout * ZYX;
        #pragma unroll
        for (int ct = 0; ct < 4; ++ct) {
            float* outp = (ct < 2) ? yr : yi;
            *reinterpret_cast<f32x4*>(outp + p*F_ + (ct & 1)*16 + lg*4) = acc[ct];
        }
    };

    // prologue: slab0 = t=0; t=1 loads in flight
    STAGE_ISSUE(0);
    STAGE_WRITE(0);
    STAGE_ISSUE(1);
    SPATIAL(0, 0,  caLo, caHi);
    SPATIAL(0, 16, cbLo, cbHi);
    WRITE(0, 0, caLo, caHi);
    WRITE(1, 0, cbLo, cbHi);

    #pragma unroll 1
    for (int t = 1; t < T_; ++t) {
        STAGE_WRITE(t & 1);                 // complete slab(t)
        if (t < T_-1) STAGE_ISSUE(t+1);     // issue next halo immediately
        const int sa = t-2 < 0 ? 0 : t-2;
        SPATIAL(t & 1, 0,  caLo, caHi);     // two independent MFMA chains
        SPATIAL(t & 1, 16, cbLo, cbHi);
        EMIT(0, caLo, caHi, sa, t-1, t-1);
        EMIT(1, cbLo, cbHi, sa, t-1, t-1);
        WRITE(0, t, caLo, caHi);
        WRITE(1, t, cbLo, cbHi);
    }
    EMIT(0, caLo, caHi, T_-2, T_-1, T_-1);  // y(7) = (s6, s7, s7)
    EMIT(1, cbLo, cbHi, T_-2, T_-1, T_-1);
}

extern "C" void kernel_launch(void* const* d_in, const int* in_sizes, int n_in,
                              void* d_out, int out_size, void* d_ws, size_t ws_size,
                              hipStream_t stream)
{
    const float* xr  = (const float*)d_in[0];
    const float* xi  = (const float*)d_in[1];
    const float* wxr = (const float*)d_in[2];
    const float* wxi = (const float*)d_in[3];
    const float* wtr = (const float*)d_in[4];
    const float* wti = (const float*)d_in[5];

    float* ws   = (float*)d_ws;
    unsigned short* wsp = (unsigned short*)(ws + 12288); // 8192 ushorts (16KB)
    unsigned short* wp  = (unsigned short*)(ws + 16384); // 12288 ushorts (24KB)
    uint2* xb           = (uint2*)(ws + 32768);          // NPTS uint2 (10.5MB)

    float* yr = (float*)d_out;
    float* yi = yr + (size_t)NPTS * F_;

    hipLaunchKernelGGL(prep_kernel, dim3(REPACK_BLKS + 40), dim3(256), 0, stream,
                       wxr, wxi, wtr, wti, xr, xi, wsp, wp, xb);
    hipLaunchKernelGGL(fused_kernel, dim3(B_*Z_*(Y_/2)), dim3(256), 0, stream,
                       xb, wsp, wp, yr, yi);
}